// Round 5
// baseline (75.942 us; speedup 1.0000x reference)
//
#include <hip/hip_runtime.h>

#define EPS_F 1e-6f
#define LOG2E 1.4426950408889634f

typedef float f4a __attribute__((ext_vector_type(4), aligned(16)));

// Force a (known-uniform) float into an SGPR.
__device__ __forceinline__ float rfl(float x) {
    return __builtin_bit_cast(float, __builtin_amdgcn_readfirstlane(__builtin_bit_cast(int, x)));
}

// Round-5 structure (r4 post-mortem: 4 structurally different kernels all land
// at dur 73-77 -> kernel term is single-digit us, residual is harness-fixed
// [40us unconditional ws poison + ~30us reset small-dispatch tax]. This round
// pushes the kernel term to its VALU floor as a decisive floor test):
//   grid = 256 blocks (exactly 1/CU) = B(8) x m-groups(2: 512 m's) x n-chunks(16).
//   block = 256 thr = 4 waves; lane owns pm=8 m's (m = mg*512 + p*64 + lane),
//   wave w sums n in [nc*64 + 16w, +16).
//   Per-CU cost model: LDS reads 4wv x 16it x 5 = 320 instrs (~1.6us worst),
//   VALU = 16it x 8p x 27ops x 2cyc ~= 6900cyc ~= 2.9us (the irreducible floor),
//   prologue/epilogue once per CU. Partials to pws (poison is free, r3-proven),
//   combine area disjoint from staging -> 2 barriers total.
// __launch_bounds__(256,1): 1 block/CU (grid-limited anyway), VGPR cap 512 --
// ~200 live regs (acc 120 + t 24 + unrolled row temps), zero spill risk.
__global__ __launch_bounds__(256, 1) void icgp_partial_kernel(
    const float* __restrict__ xa,       // (B, 1024, 1, 3)
    const float* __restrict__ feat,     // (B, 1024, 5, 3)
    const float* __restrict__ xt,       // (B, 1024, 1, 3)
    const float* __restrict__ log_std,  // (1, 5, 3)
    float* __restrict__ pws)            // (16, B*1024*15) partials
{
    // lds[0..30719]      : combine area, 4 waves x 512 m x 15 (disjoint from staging)
    // lds[30720..31743]  : feat staging, 64 rows x 16 (padded 15->16)
    // lds[31744..31999]  : xa staging,   64 rows x 4  (padded 3->4)
    __shared__ float lds[32000];        // 128 KB (static >64KB OK on gfx950: r3 ran 80KB)
    const int SF = 30720, SA = 31744;

    const int bid  = blockIdx.x;
    const int nc   = bid & 15;          // n-chunk (64 n's)
    const int mg   = (bid >> 4) & 1;    // m-group (512 m's)
    const int b    = bid >> 5;
    const int tid  = threadIdx.x;
    const int wv   = __builtin_amdgcn_readfirstlane(tid >> 6); // 0..3, uniform
    const int lane = tid & 63;
    const int n0   = nc * 64;

    // ---- stage feat (960 floats) and xa (192 floats) into padded LDS ----
    const float* __restrict__ fg = feat + ((size_t)b * 1024 + n0) * 15; // 16B-aligned
    if (tid < 240) {
        const f4a v = *(const f4a*)(fg + tid * 4);
        #pragma unroll
        for (int e = 0; e < 4; ++e) {
            const int g = tid * 4 + e;
            const int r = g / 15, c = g - r * 15;
            lds[SF + r * 16 + c] = v[e];
        }
    }
    const float* __restrict__ ag = xa + ((size_t)b * 1024 + n0) * 3;    // 16B-aligned
    if (tid < 48) {
        const f4a v = *(const f4a*)(ag + tid * 4);
        #pragma unroll
        for (int e = 0; e < 4; ++e) {
            const int g = tid * 4 + e;
            const int r = g / 3, c = g - r * 3;
            lds[SA + r * 4 + c] = v[e];
        }
    }

    // ---- coefficients: wt = exp2(coef*(xa-xt)^2), coef = -0.5*log2e/std^2 ----
    float coef[15];
    #pragma unroll
    for (int kc = 0; kc < 15; ++kc) {
        const float s = __expf(log_std[kc]) + EPS_F;
        coef[kc] = rfl(-0.5f * LOG2E / (s * s));
    }
    bool uni = true;
    #pragma unroll
    for (int k = 1; k < 5; ++k)
        #pragma unroll
        for (int c = 0; c < 3; ++c)
            uni = uni && (coef[k * 3 + c] == coef[c]);

    // xt for this lane's 8 m's: m = mg*512 + p*64 + lane (coalesced loads)
    float t[8][3];
    #pragma unroll
    for (int p = 0; p < 8; ++p) {
        const int m = mg * 512 + p * 64 + lane;
        t[p][0] = xt[(b * 1024 + m) * 3 + 0];
        t[p][1] = xt[(b * 1024 + m) * 3 + 1];
        t[p][2] = xt[(b * 1024 + m) * 3 + 2];
    }

    __syncthreads();

    float acc[8][15];
    #pragma unroll
    for (int p = 0; p < 8; ++p)
        #pragma unroll
        for (int kc = 0; kc < 15; ++kc) acc[p][kc] = 0.0f;

    const int rb = wv * 16;             // this wave's first staging row

    if (uni) {
        const float c0 = coef[0], c1 = coef[1], c2 = coef[2];
        #pragma unroll 2
        for (int i = 0; i < 16; ++i) {
            const float* __restrict__ row = &lds[SF + (rb + i) * 16];
            const f4a fA = *(const f4a*)(row);        // kc 0..3
            const f4a fB = *(const f4a*)(row + 4);    // kc 4..7
            const f4a fC = *(const f4a*)(row + 8);    // kc 8..11
            const f4a fD = *(const f4a*)(row + 12);   // kc 12..14 (+pad)
            const f4a av = *(const f4a*)(&lds[SA + (rb + i) * 4]); // xa (+pad)
            #pragma unroll
            for (int p = 0; p < 8; ++p) {
                float d0 = av.x - t[p][0]; d0 *= d0;
                float d1 = av.y - t[p][1]; d1 *= d1;
                float d2 = av.z - t[p][2]; d2 *= d2;
                const float w0 = __builtin_amdgcn_exp2f(d0 * c0);
                const float w1 = __builtin_amdgcn_exp2f(d1 * c1);
                const float w2 = __builtin_amdgcn_exp2f(d2 * c2);
                acc[p][0]  += w0 * fA.x;  acc[p][1]  += w1 * fA.y;  acc[p][2]  += w2 * fA.z;
                acc[p][3]  += w0 * fA.w;  acc[p][4]  += w1 * fB.x;  acc[p][5]  += w2 * fB.y;
                acc[p][6]  += w0 * fB.z;  acc[p][7]  += w1 * fB.w;  acc[p][8]  += w2 * fC.x;
                acc[p][9]  += w0 * fC.y;  acc[p][10] += w1 * fC.z;  acc[p][11] += w2 * fC.w;
                acc[p][12] += w0 * fD.x;  acc[p][13] += w1 * fD.y;  acc[p][14] += w2 * fD.z;
            }
        }
    } else {
        // General path: 15 exps per (m,n) (correct for arbitrary log_std).
        for (int i = 0; i < 16; ++i) {
            const float* __restrict__ row = &lds[SF + (rb + i) * 16];
            float fv[16];
            *(f4a*)(fv)      = *(const f4a*)(row);
            *(f4a*)(fv + 4)  = *(const f4a*)(row + 4);
            *(f4a*)(fv + 8)  = *(const f4a*)(row + 8);
            *(f4a*)(fv + 12) = *(const f4a*)(row + 12);
            const f4a av = *(const f4a*)(&lds[SA + (rb + i) * 4]);
            #pragma unroll
            for (int p = 0; p < 8; ++p) {
                float dd[3];
                dd[0] = av.x - t[p][0]; dd[0] *= dd[0];
                dd[1] = av.y - t[p][1]; dd[1] *= dd[1];
                dd[2] = av.z - t[p][2]; dd[2] *= dd[2];
                #pragma unroll
                for (int k = 0; k < 5; ++k)
                    #pragma unroll
                    for (int c = 0; c < 3; ++c)
                        acc[p][k * 3 + c] +=
                            __builtin_amdgcn_exp2f(dd[c] * coef[k * 3 + c]) * fv[k * 3 + c];
            }
        }
    }

    // ---- combine the 4 wave-partials in LDS, coalesced store to pws ----
    // (combine area disjoint from staging; each wave writes its own region ->
    //  no barrier needed before the writes, one barrier before the reads)
    #pragma unroll
    for (int p = 0; p < 8; ++p)
        #pragma unroll
        for (int kc = 0; kc < 15; ++kc)
            lds[wv * 7680 + (p * 64 + lane) * 15 + kc] = acc[p][kc];
            // lanes stride 15 floats, gcd(15,32)=1 -> 2 lanes/bank = free
    __syncthreads();

    float* __restrict__ pb = pws + (size_t)nc * 122880
                                 + ((size_t)b * 1024 + mg * 512) * 15;
    #pragma unroll 5
    for (int j = 0; j < 30; ++j) {
        const int oidx = j * 256 + tid;         // 0..7679, exact
        float s = 0.0f;
        #pragma unroll
        for (int w = 0; w < 4; ++w)
            s += lds[w * 7680 + oidx];           // consecutive lanes -> no conflict
        pb[oidx] = s;                            // coalesced
    }
}

// Kernel 2: sum the 16 n-chunk slices, float4-vectorized, fully coalesced.
// 30720 float4 outputs = 120 blocks x 256 threads.
__global__ __launch_bounds__(256) void icgp_reduce_kernel(
    const float* __restrict__ pws, float* __restrict__ out)
{
    const int idx4 = blockIdx.x * 256 + threadIdx.x;   // < 30720
    const f4a* __restrict__ p4 = (const f4a*)pws;
    f4a s = {0.0f, 0.0f, 0.0f, 0.0f};
    #pragma unroll
    for (int ns = 0; ns < 16; ++ns) {
        const f4a v = p4[(size_t)ns * 30720 + idx4];
        s.x += v.x; s.y += v.y; s.z += v.z; s.w += v.w;
    }
    ((f4a*)out)[idx4] = s;
}

extern "C" void kernel_launch(void* const* d_in, const int* in_sizes, int n_in,
                              void* d_out, int out_size, void* d_ws, size_t ws_size,
                              hipStream_t stream) {
    const float* xa      = (const float*)d_in[0];  // (8,1024,1,3)
    const float* feat    = (const float*)d_in[1];  // (8,1024,5,3)
    const float* xt      = (const float*)d_in[2];  // (8,1024,1,3)
    const float* log_std = (const float*)d_in[3];  // (1,5,3)
    float* out = (float*)d_out;                    // (8,1024,5,3)
    float* pws = (float*)d_ws;                     // 16 x 122880 floats = 7.86 MB

    icgp_partial_kernel<<<dim3(256), dim3(256), 0, stream>>>(xa, feat, xt, log_std, pws);
    icgp_reduce_kernel<<<dim3(120), dim3(256), 0, stream>>>(pws, out);
}